// Round 7
// baseline (312.693 us; speedup 1.0000x reference)
//
#include <hip/hip_runtime.h>

typedef short short8 __attribute__((ext_vector_type(8)));
typedef short short4v __attribute__((ext_vector_type(4)));
typedef float f32x4 __attribute__((ext_vector_type(4)));
typedef unsigned short u16;

__device__ __forceinline__ u16 f2bf(float f) {
  unsigned int u = __builtin_bit_cast(unsigned int, f);
  u = (u + 0x7FFFu + ((u >> 16) & 1u)) >> 16;
  return (u16)u;
}
__device__ __forceinline__ short8 cvt8(float4 a, float4 b) {
  short8 v;
  v[0] = (short)f2bf(a.x); v[1] = (short)f2bf(a.y);
  v[2] = (short)f2bf(a.z); v[3] = (short)f2bf(a.w);
  v[4] = (short)f2bf(b.x); v[5] = (short)f2bf(b.y);
  v[6] = (short)f2bf(b.z); v[7] = (short)f2bf(b.w);
  return v;
}
__device__ __forceinline__ short8 cvt8s(float4 a, float4 b, float s) {
  short8 v;
  v[0] = (short)f2bf(a.x * s); v[1] = (short)f2bf(a.y * s);
  v[2] = (short)f2bf(a.z * s); v[3] = (short)f2bf(a.w * s);
  v[4] = (short)f2bf(b.x * s); v[5] = (short)f2bf(b.y * s);
  v[6] = (short)f2bf(b.z * s); v[7] = (short)f2bf(b.w * s);
  return v;
}

#define NPX 147456   // 64*48*48
#define L2E 1.44269504088896f

// ---------------------------------------------------------------------------
// K0: x fp32 -> xbf bf16, plain row-major.
// ---------------------------------------------------------------------------
__global__ __launch_bounds__(256)
void xcvt_kernel(const float* __restrict__ x, u16* __restrict__ xbf)
{
  size_t c = ((size_t)blockIdx.x * 256 + threadIdx.x) * 8;
  const float4* p = (const float4*)(x + c);
  *(short8*)(xbf + c) = cvt8(p[0], p[1]);
}

// ---------------------------------------------------------------------------
// Fused scan, 6-wave split. 768 blocks x 384 threads; block owns 16 seqs of
// one direction. Wave w = 2s+h: slice s (hd [16s,16s+16)), h=0 -> gates i,f;
// h=1 -> gates g,o. Per step: x tile (16x192 bf16) read from double-buffered
// swizzled LDS (staged by all 384 threads, 16 B each); 12 x-MFMA + 4 h-MFMA
// per wave; h=1 passes accs to h=0 via LDS (lane-aligned); h=0 does the cell
// update with exp2-native activations (log2e pre-folded into W/U/bias).
// ---------------------------------------------------------------------------
__global__ __launch_bounds__(384)
void fused_scan_kernel(const u16* __restrict__ xbf,
    const float* __restrict__ wi0, const float* __restrict__ wi1,
    const float* __restrict__ wi2, const float* __restrict__ wi3,
    const float* __restrict__ u0, const float* __restrict__ u1,
    const float* __restrict__ u2, const float* __restrict__ u3,
    const float* __restrict__ bi0, const float* __restrict__ bh0,
    const float* __restrict__ bi1, const float* __restrict__ bh1,
    const float* __restrict__ bi2, const float* __restrict__ bh2,
    const float* __restrict__ bi3, const float* __restrict__ bh3,
    u16* __restrict__ comb)
{
  __shared__ u16 xl[2][3072];          // [16 seq][192 k] bf16, XOR-swizzled
  __shared__ u16 hl[2][1152];          // [16 seq][72] (48 h + 24 zero pad)
  __shared__ f32x4 xga[3][64];         // gate-g acc handoff (16 B/lane)
  __shared__ f32x4 xgo[3][64];         // gate-o acc handoff

  const int tid  = threadIdx.x;
  const int lane = tid & 63;
  const int wv   = tid >> 6;           // 0..5
  const int s    = wv >> 1;            // hd slice
  const int h    = wv & 1;             // 0: i,f   1: g,o
  const int cl   = lane & 15;
  const int kg   = lane >> 4;
  const int W    = blockIdx.x;         // 0..767
  const int dir  = W / 192;
  const int g    = W - dir * 192;
  const int bb   = g / 3;
  const int rcb  = (g - bb * 3) * 16;
  const bool vert = dir < 2;
  const bool bwd  = (dir & 1) != 0;

  const float* wp  = dir == 0 ? wi0 : dir == 1 ? wi1 : dir == 2 ? wi2 : wi3;
  const float* up  = dir == 0 ? u0  : dir == 1 ? u1  : dir == 2 ? u2  : u3;
  const float* bip = dir == 0 ? bi0 : dir == 1 ? bi1 : dir == 2 ? bi2 : bi3;
  const float* bhp = dir == 0 ? bh0 : dir == 1 ? bh1 : dir == 2 ? bh2 : bh3;

  const int tp0 = bwd ? 47 : 0;
  const int dpx = (vert ? 48 : 1) * (bwd ? -1 : 1);

  // staging thread mapping: chunk tid -> (seq_l, k0)
  const int seq_l = tid / 24;
  const int k0    = (tid % 24) * 8;
  const int rc_t  = rcb + seq_l;
  const int px_t0 = vert ? (bb * 48 + tp0) * 48 + rc_t
                         : (bb * 48 + rc_t) * 48 + tp0;
  const int swz_w = (seq_l * 192 + k0) ^ ((seq_l & 7) << 3);

  // ---- stage x(t=0)
  short8 s0 = *(const short8*)(xbf + (size_t)px_t0 * 192 + k0);
  *(short8*)&xl[0][swz_w] = s0;
  // in-loop source pointer starts at x(t=1)
  const u16* xsrc = xbf + (size_t)(px_t0 + dpx) * 192 + k0;
  const ptrdiff_t xstep = (ptrdiff_t)dpx * 192;

  // ---- weight fragments: this wave's two gate tiles
  const int g0 = h ? 2 : 0;
  const int g1 = h ? 3 : 1;
  const float s0f = h ? 2.0f * L2E : L2E;   // gate g needs 2*log2e
  const float s1f = L2E;

  short8 wf[2][6], uf[2][2];
  f32x4 bv[2];
  #pragma unroll
  for (int j = 0; j < 2; ++j) {
    int gj = j ? g1 : g0;
    float sc = j ? s1f : s0f;
    int n = gj * 48 + s * 16 + cl;
    #pragma unroll
    for (int kk = 0; kk < 6; ++kk) {
      const float4* p = (const float4*)(wp + n * 192 + kk * 32 + kg * 8);
      wf[j][kk] = cvt8s(p[0], p[1], sc);
    }
    {
      const float4* p = (const float4*)(up + n * 48 + kg * 8);
      uf[j][0] = cvt8s(p[0], p[1], sc);
    }
    if (kg < 2) {
      const float4* p = (const float4*)(up + n * 48 + 32 + kg * 8);
      uf[j][1] = cvt8s(p[0], p[1], sc);
    } else {
      short8 z = {}; uf[j][1] = z;
    }
    #pragma unroll
    for (int r = 0; r < 4; ++r) {
      int nb = gj * 48 + s * 16 + kg * 4 + r;
      bv[j][r] = (bip[nb] + bhp[nb]) * sc;
    }
  }

  // zero both h buffers
  for (int i = tid; i < 2304; i += 384) (&hl[0][0])[i] = 0;
  __syncthreads();

  float c[4] = {0.f, 0.f, 0.f, 0.f};
  // comb pointer (h=0 waves): lane -> seq rcb+cl, hd slice s
  const int rc_l = rcb + cl;
  const int px_l = vert ? (bb * 48 + tp0) * 48 + rc_l
                        : (bb * 48 + rc_l) * 48 + tp0;
  u16* cbp = comb + (size_t)dir * NPX * 48 + (size_t)px_l * 48 + s * 16 + kg * 4;
  const ptrdiff_t cstep = (ptrdiff_t)dpx * 48;

  int cur = 0, hcur = 0;

  for (int t = 0; t < 48; ++t) {
    // issue next-tile global load early (lands during MFMA phase)
    short8 sa;
    if (t < 47) { sa = *(const short8*)xsrc; xsrc += xstep; }

    // fragments from LDS
    short8 xf[6];
    #pragma unroll
    for (int kk = 0; kk < 6; ++kk)
      xf[kk] = *(const short8*)&xl[cur][(cl * 192 + kk * 32 + kg * 8) ^ ((cl & 7) << 3)];
    short8 hb0 = *(const short8*)&hl[hcur][cl * 72 + kg * 8];
    short8 hb1 = *(const short8*)&hl[hcur][cl * 72 + 32 + kg * 8];

    f32x4 a0 = bv[0], a1 = bv[1];
    #pragma unroll
    for (int kk = 0; kk < 6; ++kk) {
      a0 = __builtin_amdgcn_mfma_f32_16x16x32_bf16(wf[0][kk], xf[kk], a0, 0, 0, 0);
      a1 = __builtin_amdgcn_mfma_f32_16x16x32_bf16(wf[1][kk], xf[kk], a1, 0, 0, 0);
    }
    a0 = __builtin_amdgcn_mfma_f32_16x16x32_bf16(uf[0][0], hb0, a0, 0, 0, 0);
    a1 = __builtin_amdgcn_mfma_f32_16x16x32_bf16(uf[1][0], hb0, a1, 0, 0, 0);
    a0 = __builtin_amdgcn_mfma_f32_16x16x32_bf16(uf[0][1], hb1, a0, 0, 0, 0);
    a1 = __builtin_amdgcn_mfma_f32_16x16x32_bf16(uf[1][1], hb1, a1, 0, 0, 0);

    if (h) { xga[s][lane] = a0; xgo[s][lane] = a1; }
    __syncthreads();

    if (!h) {
      f32x4 aG = xga[s][lane];
      f32x4 aO = xgo[s][lane];
      short4v h4;
      #pragma unroll
      for (int r = 0; r < 4; ++r) {
        float ii = __builtin_amdgcn_rcpf(1.0f + __builtin_exp2f(-a0[r]));
        float ff = __builtin_amdgcn_rcpf(1.0f + __builtin_exp2f(-a1[r]));
        float gg = 1.0f - 2.0f * __builtin_amdgcn_rcpf(1.0f + __builtin_exp2f(aG[r]));
        float oo = __builtin_amdgcn_rcpf(1.0f + __builtin_exp2f(-aO[r]));
        float cc = ff * c[r] + ii * gg;
        c[r] = cc;
        float th = 1.0f - 2.0f * __builtin_amdgcn_rcpf(1.0f + __builtin_exp2f(cc * (2.0f * L2E)));
        h4[r] = (short)f2bf(oo * th);
      }
      *(short4v*)&hl[hcur ^ 1][cl * 72 + s * 16 + kg * 4] = h4;
      *(short4v*)cbp = h4;
      cbp += cstep;
    }
    if (t < 47) *(short8*)&xl[cur ^ 1][swz_w] = sa;
    __syncthreads();
    cur ^= 1; hcur ^= 1;
  }
}

// ---------------------------------------------------------------------------
// K3: out[px][c] = comb4[px][:] @ proj_w[c][:] + proj_b[c], fp32. (unchanged)
// ---------------------------------------------------------------------------
__global__ __launch_bounds__(256)
void proj_kernel(const u16* __restrict__ comb,
                 const float* __restrict__ pw,
                 const float* __restrict__ pb,
                 float* __restrict__ out)
{
  __shared__ u16 al[12288];
  const int tid  = threadIdx.x;
  const int lane = tid & 63;
  const int wv   = tid >> 6;
  const int cl   = lane & 15;
  const int kg   = lane >> 4;
  const int pxb  = blockIdx.x * 64;

  #pragma unroll
  for (int i = 0; i < 6; ++i) {
    int ch = tid + 256 * i;
    int pxl = ch / 24;
    int kk0 = (ch % 24) << 3;
    int d   = kk0 / 48;
    short8 v = *(const short8*)(comb + ((size_t)d * NPX + pxb + pxl) * 48 + (kk0 - d * 48));
    *(short8*)&al[(pxl * 192 + kk0) ^ ((pxl & 7) << 3)] = v;
  }

  short8 wf[3][6];
  #pragma unroll
  for (int nt = 0; nt < 3; ++nt) {
    int n = wv * 48 + nt * 16 + cl;
    #pragma unroll
    for (int kk = 0; kk < 6; ++kk) {
      const float4* p = (const float4*)(pw + n * 192 + kk * 32 + kg * 8);
      wf[nt][kk] = cvt8(p[0], p[1]);
    }
  }
  f32x4 bvv[3];
  #pragma unroll
  for (int nt = 0; nt < 3; ++nt)
    #pragma unroll
    for (int r = 0; r < 4; ++r)
      bvv[nt][r] = pb[wv * 48 + nt * 16 + kg * 4 + r];

  __syncthreads();

  f32x4 acc[3][4];
  #pragma unroll
  for (int nt = 0; nt < 3; ++nt)
    #pragma unroll
    for (int mi = 0; mi < 4; ++mi) acc[nt][mi] = bvv[nt];

  #pragma unroll
  for (int kk = 0; kk < 6; ++kk) {
    short8 bfr[4];
    #pragma unroll
    for (int mi = 0; mi < 4; ++mi) {
      int row = mi * 16 + cl;
      bfr[mi] = *(const short8*)&al[(row * 192 + kk * 32 + kg * 8) ^ ((row & 7) << 3)];
    }
    #pragma unroll
    for (int nt = 0; nt < 3; ++nt)
      #pragma unroll
      for (int mi = 0; mi < 4; ++mi)
        acc[nt][mi] = __builtin_amdgcn_mfma_f32_16x16x32_bf16(wf[nt][kk], bfr[mi], acc[nt][mi], 0, 0, 0);
  }

  #pragma unroll
  for (int nt = 0; nt < 3; ++nt)
    #pragma unroll
    for (int mi = 0; mi < 4; ++mi) {
      size_t o = (size_t)(pxb + mi * 16 + cl) * 192 + wv * 48 + nt * 16 + kg * 4;
      *(f32x4*)(out + o) = acc[nt][mi];
    }
}

extern "C" void kernel_launch(void* const* d_in, const int* in_sizes, int n_in,
                              void* d_out, int out_size, void* d_ws, size_t ws_size,
                              hipStream_t stream) {
  const float* x = (const float*)d_in[0];
  u16* xbf  = (u16*)d_ws;                              // 56.6 MB row-major bf16 x
  u16* comb = (u16*)d_ws + (size_t)NPX * 192;          // 56.6 MB

  xcvt_kernel<<<13824, 256, 0, stream>>>(x, xbf);

  fused_scan_kernel<<<768, 384, 0, stream>>>(
      xbf,
      (const float*)d_in[1], (const float*)d_in[5],
      (const float*)d_in[9], (const float*)d_in[13],
      (const float*)d_in[2], (const float*)d_in[6],
      (const float*)d_in[10], (const float*)d_in[14],
      (const float*)d_in[3],  (const float*)d_in[4],
      (const float*)d_in[7],  (const float*)d_in[8],
      (const float*)d_in[11], (const float*)d_in[12],
      (const float*)d_in[15], (const float*)d_in[16],
      comb);

  proj_kernel<<<2304, 256, 0, stream>>>(
      comb, (const float*)d_in[17], (const float*)d_in[18], (float*)d_out);
}

// Round 8
// 228.785 us; speedup vs baseline: 1.3668x; 1.3668x over previous
//
#include <hip/hip_runtime.h>

typedef short short8 __attribute__((ext_vector_type(8)));
typedef short short4v __attribute__((ext_vector_type(4)));
typedef float f32x4 __attribute__((ext_vector_type(4)));
typedef unsigned short u16;

__device__ __forceinline__ u16 f2bf(float f) {
  unsigned int u = __builtin_bit_cast(unsigned int, f);
  u = (u + 0x7FFFu + ((u >> 16) & 1u)) >> 16;
  return (u16)u;
}
__device__ __forceinline__ short8 cvt8(float4 a, float4 b) {
  short8 v;
  v[0] = (short)f2bf(a.x); v[1] = (short)f2bf(a.y);
  v[2] = (short)f2bf(a.z); v[3] = (short)f2bf(a.w);
  v[4] = (short)f2bf(b.x); v[5] = (short)f2bf(b.y);
  v[6] = (short)f2bf(b.z); v[7] = (short)f2bf(b.w);
  return v;
}
__device__ __forceinline__ short8 cvt8s(float4 a, float4 b, float s) {
  short8 v;
  v[0] = (short)f2bf(a.x * s); v[1] = (short)f2bf(a.y * s);
  v[2] = (short)f2bf(a.z * s); v[3] = (short)f2bf(a.w * s);
  v[4] = (short)f2bf(b.x * s); v[5] = (short)f2bf(b.y * s);
  v[6] = (short)f2bf(b.z * s); v[7] = (short)f2bf(b.w * s);
  return v;
}

#define NPX 147456   // 64*48*48
#define L2E 1.44269504088896f

// ---------------------------------------------------------------------------
// K0: x fp32 -> xbf bf16, plain row-major.
// ---------------------------------------------------------------------------
__global__ __launch_bounds__(256)
void xcvt_kernel(const float* __restrict__ x, u16* __restrict__ xbf)
{
  size_t c = ((size_t)blockIdx.x * 256 + threadIdx.x) * 8;
  const float4* p = (const float4*)(x + c);
  *(short8*)(xbf + c) = cvt8(p[0], p[1]);
}

// ---------------------------------------------------------------------------
// Fused scan, R6 structure + cross-step x-pipeline. 768 blocks x 3 waves;
// block owns 16 seqs of one direction; wave wv owns hd-slice [16wv,16wv+16)
// = gate tiles {wv,3+wv,6+wv,9+wv}. During step t the wave builds
// nxt = bias + Wih@x(t+1) (24 independent MFMAs that overlap the epilogue /
// barrier), so the serial chain is only: h-read -> 2 h-MFMA -> epilogue ->
// h-write -> barrier. exp2-native activations (log2e folded into W/U/bias).
// ---------------------------------------------------------------------------
__global__ __launch_bounds__(192)
void fused_scan_kernel(const u16* __restrict__ xbf,
    const float* __restrict__ wi0, const float* __restrict__ wi1,
    const float* __restrict__ wi2, const float* __restrict__ wi3,
    const float* __restrict__ u0, const float* __restrict__ u1,
    const float* __restrict__ u2, const float* __restrict__ u3,
    const float* __restrict__ bi0, const float* __restrict__ bh0,
    const float* __restrict__ bi1, const float* __restrict__ bh1,
    const float* __restrict__ bi2, const float* __restrict__ bh2,
    const float* __restrict__ bi3, const float* __restrict__ bh3,
    u16* __restrict__ comb)
{
  __shared__ u16 hl[2][1152];          // [16 seq][72] (48 h + 24 zero pad)
  const int tid  = threadIdx.x;
  const int lane = tid & 63;
  const int wv   = tid >> 6;           // 0..2 -> hd slice
  const int cl   = lane & 15;
  const int kg   = lane >> 4;
  const int W    = blockIdx.x;         // 0..767
  const int dir  = W / 192;
  const int g    = W - dir * 192;
  const int bb   = g / 3;
  const int rc   = (g - bb * 3) * 16 + cl;
  const bool vert = dir < 2;
  const bool bwd  = (dir & 1) != 0;

  const float* wp  = dir == 0 ? wi0 : dir == 1 ? wi1 : dir == 2 ? wi2 : wi3;
  const float* up  = dir == 0 ? u0  : dir == 1 ? u1  : dir == 2 ? u2  : u3;
  const float* bip = dir == 0 ? bi0 : dir == 1 ? bi1 : dir == 2 ? bi2 : bi3;
  const float* bhp = dir == 0 ? bh0 : dir == 1 ? bh1 : dir == 2 ? bh2 : bh3;

  const int tp0 = bwd ? 47 : 0;
  const int dpx = (vert ? 48 : 1) * (bwd ? -1 : 1);
  const int px0 = vert ? (bb * 48 + tp0) * 48 + rc : (bb * 48 + rc) * 48 + tp0;

  // ---- x fragment pointer (B-operand: lane(cl,kg) -> seq=cl, k=kg*8+..)
  const u16* xp = xbf + (size_t)px0 * 192 + kg * 8;
  const ptrdiff_t xstep = (ptrdiff_t)dpx * 192;

  // load x(0) frags immediately (latency hides under weight setup)
  short8 xf[6];
  #pragma unroll
  for (int kk = 0; kk < 6; ++kk) xf[kk] = *(const short8*)(xp + kk * 32);

  // ---- weight fragments, log2e-scaled (gate g: 2*log2e)
  short8 wf[4][6], uf[4][2];
  f32x4 bv[4];
  #pragma unroll
  for (int q = 0; q < 4; ++q) {
    const float sc = (q == 2) ? 2.0f * L2E : L2E;
    int n = q * 48 + wv * 16 + cl;
    #pragma unroll
    for (int kk = 0; kk < 6; ++kk) {
      const float4* p = (const float4*)(wp + n * 192 + kk * 32 + kg * 8);
      wf[q][kk] = cvt8s(p[0], p[1], sc);
    }
    {
      const float4* p = (const float4*)(up + n * 48 + kg * 8);
      uf[q][0] = cvt8s(p[0], p[1], sc);
    }
    if (kg < 2) {
      const float4* p = (const float4*)(up + n * 48 + 32 + kg * 8);
      uf[q][1] = cvt8s(p[0], p[1], sc);
    } else {
      short8 z = {}; uf[q][1] = z;
    }
    #pragma unroll
    for (int r = 0; r < 4; ++r) {
      int nb = q * 48 + wv * 16 + kg * 4 + r;
      bv[q][r] = (bip[nb] + bhp[nb]) * sc;
    }
  }

  // zero both h buffers (t=0 sees h=0; pads stay zero)
  for (int i = tid; i < 2304; i += 192) (&hl[0][0])[i] = 0;
  __syncthreads();

  // ---- prologue: pA = bias + Wih@x(0); then refill xf with x(1)
  f32x4 pA[4], pB[4];
  #pragma unroll
  for (int q = 0; q < 4; ++q) pA[q] = bv[q];
  #pragma unroll
  for (int kk = 0; kk < 6; ++kk)
    #pragma unroll
    for (int q = 0; q < 4; ++q)
      pA[q] = __builtin_amdgcn_mfma_f32_16x16x32_bf16(wf[q][kk], xf[kk], pA[q], 0, 0, 0);
  xp += xstep;
  #pragma unroll
  for (int kk = 0; kk < 6; ++kk) xf[kk] = *(const short8*)(xp + kk * 32);

  float c[4] = {0.f, 0.f, 0.f, 0.f};
  int hcur = 0;
  u16* cbp = comb + (size_t)dir * NPX * 48 + (size_t)px0 * 48 + wv * 16 + kg * 4;
  const ptrdiff_t cstep = (ptrdiff_t)dpx * 48;

  auto STEP = [&](f32x4 (&cur)[4], f32x4 (&nxt)[4], int t) {
    // serial inputs first: h of previous step
    short8 hb0 = *(const short8*)&hl[hcur][cl * 72 + kg * 8];
    short8 hb1 = *(const short8*)&hl[hcur][cl * 72 + 32 + kg * 8];

    // pipelined x-part for step t+1 (independent of h; overlaps everything)
    if (t < 47) {
      #pragma unroll
      for (int q = 0; q < 4; ++q) nxt[q] = bv[q];
      #pragma unroll
      for (int kk = 0; kk < 6; ++kk)
        #pragma unroll
        for (int q = 0; q < 4; ++q)
          nxt[q] = __builtin_amdgcn_mfma_f32_16x16x32_bf16(wf[q][kk], xf[kk], nxt[q], 0, 0, 0);
      if (t < 46) {                    // refill xf with x(t+2)
        xp += xstep;
        #pragma unroll
        for (int kk = 0; kk < 6; ++kk) xf[kk] = *(const short8*)(xp + kk * 32);
      }
    }

    // serial chain: 2 h-MFMAs
    #pragma unroll
    for (int q = 0; q < 4; ++q)
      cur[q] = __builtin_amdgcn_mfma_f32_16x16x32_bf16(uf[q][0], hb0, cur[q], 0, 0, 0);
    #pragma unroll
    for (int q = 0; q < 4; ++q)
      cur[q] = __builtin_amdgcn_mfma_f32_16x16x32_bf16(uf[q][1], hb1, cur[q], 0, 0, 0);

    // epilogue: lane -> seq=cl, hd = wv*16 + kg*4 + r
    short4v h4;
    #pragma unroll
    for (int r = 0; r < 4; ++r) {
      float ii = __builtin_amdgcn_rcpf(1.0f + __builtin_exp2f(-cur[0][r]));
      float ff = __builtin_amdgcn_rcpf(1.0f + __builtin_exp2f(-cur[1][r]));
      float gg = 1.0f - 2.0f * __builtin_amdgcn_rcpf(1.0f + __builtin_exp2f(cur[2][r]));
      float oo = __builtin_amdgcn_rcpf(1.0f + __builtin_exp2f(-cur[3][r]));
      float cc = ff * c[r] + ii * gg;
      c[r] = cc;
      float th = 1.0f - 2.0f * __builtin_amdgcn_rcpf(1.0f + __builtin_exp2f(cc * (2.0f * L2E)));
      h4[r] = (short)f2bf(oo * th);
    }
    *(short4v*)&hl[hcur ^ 1][cl * 72 + wv * 16 + kg * 4] = h4;
    *(short4v*)cbp = h4;
    cbp += cstep;
    __syncthreads();
    hcur ^= 1;
  };

  for (int it = 0; it < 24; ++it) {
    STEP(pA, pB, 2 * it);
    STEP(pB, pA, 2 * it + 1);
  }
}

// ---------------------------------------------------------------------------
// K3: out[px][c] = comb4[px][:] @ proj_w[c][:] + proj_b[c], fp32. (unchanged)
// ---------------------------------------------------------------------------
__global__ __launch_bounds__(256)
void proj_kernel(const u16* __restrict__ comb,
                 const float* __restrict__ pw,
                 const float* __restrict__ pb,
                 float* __restrict__ out)
{
  __shared__ u16 al[12288];
  const int tid  = threadIdx.x;
  const int lane = tid & 63;
  const int wv   = tid >> 6;
  const int cl   = lane & 15;
  const int kg   = lane >> 4;
  const int pxb  = blockIdx.x * 64;

  #pragma unroll
  for (int i = 0; i < 6; ++i) {
    int ch = tid + 256 * i;
    int pxl = ch / 24;
    int kk0 = (ch % 24) << 3;
    int d   = kk0 / 48;
    short8 v = *(const short8*)(comb + ((size_t)d * NPX + pxb + pxl) * 48 + (kk0 - d * 48));
    *(short8*)&al[(pxl * 192 + kk0) ^ ((pxl & 7) << 3)] = v;
  }

  short8 wf[3][6];
  #pragma unroll
  for (int nt = 0; nt < 3; ++nt) {
    int n = wv * 48 + nt * 16 + cl;
    #pragma unroll
    for (int kk = 0; kk < 6; ++kk) {
      const float4* p = (const float4*)(pw + n * 192 + kk * 32 + kg * 8);
      wf[nt][kk] = cvt8(p[0], p[1]);
    }
  }
  f32x4 bvv[3];
  #pragma unroll
  for (int nt = 0; nt < 3; ++nt)
    #pragma unroll
    for (int r = 0; r < 4; ++r)
      bvv[nt][r] = pb[wv * 48 + nt * 16 + kg * 4 + r];

  __syncthreads();

  f32x4 acc[3][4];
  #pragma unroll
  for (int nt = 0; nt < 3; ++nt)
    #pragma unroll
    for (int mi = 0; mi < 4; ++mi) acc[nt][mi] = bvv[nt];

  #pragma unroll
  for (int kk = 0; kk < 6; ++kk) {
    short8 bfr[4];
    #pragma unroll
    for (int mi = 0; mi < 4; ++mi) {
      int row = mi * 16 + cl;
      bfr[mi] = *(const short8*)&al[(row * 192 + kk * 32 + kg * 8) ^ ((row & 7) << 3)];
    }
    #pragma unroll
    for (int nt = 0; nt < 3; ++nt)
      #pragma unroll
      for (int mi = 0; mi < 4; ++mi)
        acc[nt][mi] = __builtin_amdgcn_mfma_f32_16x16x32_bf16(wf[nt][kk], bfr[mi], acc[nt][mi], 0, 0, 0);
  }

  #pragma unroll
  for (int nt = 0; nt < 3; ++nt)
    #pragma unroll
    for (int mi = 0; mi < 4; ++mi) {
      size_t o = (size_t)(pxb + mi * 16 + cl) * 192 + wv * 48 + nt * 16 + kg * 4;
      *(f32x4*)(out + o) = acc[nt][mi];
    }
}

extern "C" void kernel_launch(void* const* d_in, const int* in_sizes, int n_in,
                              void* d_out, int out_size, void* d_ws, size_t ws_size,
                              hipStream_t stream) {
  const float* x = (const float*)d_in[0];
  u16* xbf  = (u16*)d_ws;                              // 56.6 MB row-major bf16 x
  u16* comb = (u16*)d_ws + (size_t)NPX * 192;          // 56.6 MB

  xcvt_kernel<<<13824, 256, 0, stream>>>(x, xbf);

  fused_scan_kernel<<<768, 192, 0, stream>>>(
      xbf,
      (const float*)d_in[1], (const float*)d_in[5],
      (const float*)d_in[9], (const float*)d_in[13],
      (const float*)d_in[2], (const float*)d_in[6],
      (const float*)d_in[10], (const float*)d_in[14],
      (const float*)d_in[3],  (const float*)d_in[4],
      (const float*)d_in[7],  (const float*)d_in[8],
      (const float*)d_in[11], (const float*)d_in[12],
      (const float*)d_in[15], (const float*)d_in[16],
      comb);

  proj_kernel<<<2304, 256, 0, stream>>>(
      comb, (const float*)d_in[17], (const float*)d_in[18], (float*)d_out);
}